// Round 11
// baseline (395.651 us; speedup 1.0000x reference)
//
#include <hip/hip_runtime.h>

// GCN regressor: 2x (mean-aggregate + linear+ReLU) + per-graph mean + MLP head.
// N=50000 nodes, E=800000 edges, D_IN=128, H1=256, H2=128, G=256.
// R25: dispatch-count experiment (8 -> 6), zero added sync cost:
//  - memset dispatch DELETED: no cursor (fixed per-(block,group) partE slices,
//    BCAP=48 = mean+8sigma; counts published in bcnt[256][ngrp], fully written
//    so no zeroing); gsum+done zeroed in gemm1 prologue (dispatch-ordered
//    before gemm2's atomics).
//  - final_kernel MERGED into gemm2: threadfence + done-counter; blocks 0..255
//    spin until done==gridDim.x (deadlock-free: non-spinners always exit and
//    release slots), then atomic-load gsum (XCD-coherent) into LDS + head MLP.
//  Rationale: budget audit R24 - sum of all defensible per-dispatch estimates
//  =~170us vs 279.6 measured -> ~110us must be inter-dispatch overhead
//  (~13us x 8). R13's "merge neutral" used costly lookback sync; this is the
//  sync-free test. Predict ~250 if gap theory right, ~270 if wrong.
// AGGS ARE CLOSED (evidence, 5 structural probes, all 54-58us):
//  R16 chain hoist -2.6; R17/R18 economy null; R19 XCD-shard FETCH-27% but
//  time +4% => bound = per-request service rate. Do not touch the gather.
// Closed: R6 chunk-gather 7x; R8/R9 grid.sync 2x; R11 agg-GEMM fusion;
//  R13 lookback merge; R17 launch_bounds spill; R20 per-edge global atomics;
//  R21/R22 scattered 4B writes (~30us/800K invariant; fix = coarser writes).

#define NUM_GRAPHS 256
#define MAXDEG 64
#define GSHIFT 8              // 256-node groups
#define BCAP 48               // per-(block,group) slice cap (mean 15.9 + 8sig)
#define GSLICE (256 * BCAP)   // entries per group region (12288)
#define CHUNK_MAX 3200        // per-block edge chunk cap (E=800000/256 = 3125)

// misc_kernel block partition
#define PART_B0 0
#define PART_NB 256
#define CST_B0 (PART_B0 + PART_NB)
#define CST_NB 512
#define GST_B0 (CST_B0 + CST_NB)
#define GST_NB 64
#define WT1_B0 (GST_B0 + GST_NB)
#define WT1_NB 16
#define WT2_B0 (WT1_B0 + WT1_NB)
#define WT2_NB 32
#define MISC_NB (WT2_B0 + WT2_NB)

typedef __attribute__((ext_vector_type(8))) short bf16x8;
typedef __attribute__((ext_vector_type(4))) float f32x4;
typedef __attribute__((ext_vector_type(4))) unsigned int u32x4;

__device__ inline unsigned short f2bf(float f) {  // round-to-nearest-even
    unsigned u = __float_as_uint(f);
    return (unsigned short)((u + 0x7fff + ((u >> 16) & 1)) >> 16);
}
__device__ inline float bflo(unsigned u) { return __uint_as_float(u << 16); }
__device__ inline float bfhi(unsigned u) { return __uint_as_float(u & 0xffff0000u); }

// ---------------- misc: edge partition (fixed slices) + gstart + h cast + weight transposes ----------------

__launch_bounds__(256)
__global__ void misc_kernel(const int* __restrict__ dst, const int* __restrict__ src,
                            const int* __restrict__ gids,
                            const float* __restrict__ h,
                            const float* __restrict__ W1, const float* __restrict__ W2,
                            int* __restrict__ bcnt, unsigned* __restrict__ partE,
                            int* __restrict__ gstart,
                            unsigned short* __restrict__ hb,
                            unsigned short* __restrict__ Wt1, unsigned short* __restrict__ Wt2,
                            int N, int E) {
    int b = blockIdx.x, tid = threadIdx.x;
    if (b < CST_B0) {  // partition: hist -> scan -> LDS compaction -> coalesced flush
        __shared__ unsigned lcnt[256];
        __shared__ unsigned sbuf[256];
        __shared__ unsigned lbase[257];
        __shared__ unsigned comp[CHUNK_MAX];
        int b0 = b - PART_B0;
        int chunk = (E + PART_NB - 1) / PART_NB;
        int ebeg = b0 * chunk;
        int eend = ebeg + chunk; if (eend > E) eend = E;
        int ecount = eend - ebeg; if (ecount < 0) ecount = 0;

        lcnt[tid] = 0;
        __syncthreads();
        for (int e = ebeg + tid; e < eend; e += 256) {
            int d = __builtin_nontemporal_load(&dst[e]);
            atomicAdd(&lcnt[d >> GSHIFT], 1u);
        }
        __syncthreads();
        // Kogge-Stone inclusive scan over 256 bins -> exclusive lbase
        unsigned v = lcnt[tid];
        sbuf[tid] = v;
        __syncthreads();
        #pragma unroll
        for (int dd = 1; dd < 256; dd <<= 1) {
            unsigned t = (tid >= dd) ? sbuf[tid - dd] : 0u;
            __syncthreads();
            sbuf[tid] += t;
            __syncthreads();
        }
        lbase[tid] = sbuf[tid] - v;
        if (tid == 255) lbase[256] = sbuf[255];
        // publish per-(block,group) count (coalesced, no atomics, no memset)
        bcnt[b0 * 256 + tid] = (int)(v < BCAP ? v : BCAP);
        lcnt[tid] = 0;
        __syncthreads();
        // sweep 2: LDS scatter into group-ordered compacted buffer
        for (int e = ebeg + tid; e < eend; e += 256) {
            int d = __builtin_nontemporal_load(&dst[e]);
            int s = __builtin_nontemporal_load(&src[e]);
            int g = d >> GSHIFT;
            unsigned r = atomicAdd(&lcnt[g], 1u) + lbase[g];
            if (r < (unsigned)CHUNK_MAX)  // always true for E=800000
                comp[r] = ((unsigned)s << GSHIFT) | (unsigned)(d & 255);
        }
        __syncthreads();
        // coalesced flush into fixed slice: partE[g*GSLICE + b0*BCAP + off]
        for (int i = tid; i < ecount; i += 256) {
            int lo = 0, hi = 256;
            while (hi - lo > 1) {  // find g: lbase[g] <= i < lbase[g+1]
                int mid = (lo + hi) >> 1;
                if (lbase[mid] <= (unsigned)i) lo = mid; else hi = mid;
            }
            unsigned off = (unsigned)i - lbase[lo];
            if (off < (unsigned)BCAP)  // statistically unreachable guard
                __builtin_nontemporal_store(
                    comp[i], &partE[(size_t)lo * GSLICE + (unsigned)b0 * BCAP + off]);
        }
    } else if (b < GST_B0) {  // cast h -> bf16 (float4 granules)
        int lid = (b - CST_B0) * 256 + tid;
        int total4 = N * 32;
        for (int i = lid; i < total4; i += CST_NB * 256) {
            float4 v = *(const float4*)(h + (size_t)i * 4);
            ushort4 o;
            o.x = f2bf(v.x); o.y = f2bf(v.y); o.z = f2bf(v.z); o.w = f2bf(v.w);
            *(ushort4*)(hb + (size_t)i * 4) = o;
        }
    } else if (b < WT1_B0) {  // graph segment starts (gids sorted)
        int lid = (b - GST_B0) * 256 + tid;
        for (int n = lid; n < N; n += GST_NB * 256) {
            int g = gids[n];
            int gp = (n == 0) ? -1 : gids[n - 1];
            for (int x = gp + 1; x <= g; ++x) gstart[x] = n;
            if (n == N - 1)
                for (int x = g + 1; x <= NUM_GRAPHS; ++x) gstart[x] = N;
        }
    } else if (b < WT2_B0) {  // Wt1[n][k] = bf16(W1[k][n]), K=128
        int lid = (b - WT1_B0) * 256 + tid;
        for (int i = lid; i < 256 * 128; i += WT1_NB * 256)
            Wt1[i] = f2bf(W1[(size_t)(i & 127) * 256 + (i >> 7)]);
    } else {  // Wt2[n][k] = bf16(W2[k][n]), K=256
        int lid = (b - WT2_B0) * 256 + tid;
        for (int i = lid; i < 256 * 256; i += WT2_NB * 256)
            Wt2[i] = f2bf(W2[(size_t)(i & 255) * 256 + (i >> 8)]);
    }
}

// ---------------- ELL build: 256-node groups, full tile staged in LDS ----------------
// Per-group slices flattened via a 256-wide scan of bcnt; rank scatter is
// LDS-local; global flush = 32KB u32x4 stream. No scattered global writes.

__launch_bounds__(256)
__global__ void build_kernel(const unsigned* __restrict__ partE,
                             const int* __restrict__ bcnt,
                             int* __restrict__ cnt, unsigned short* __restrict__ eidx,
                             int N) {
    __shared__ unsigned short es[256 * MAXDEG];  // 32KB ELL tile
    __shared__ unsigned hist[256];
    __shared__ unsigned sb[256];
    __shared__ unsigned bpre[257];
    int g = blockIdx.x, tid = threadIdx.x;
    hist[tid] = 0;
    unsigned v = (unsigned)bcnt[tid * 256 + g];  // block tid's count for group g
    sb[tid] = v;
    __syncthreads();
    #pragma unroll
    for (int dd = 1; dd < 256; dd <<= 1) {
        unsigned t = (tid >= dd) ? sb[tid - dd] : 0u;
        __syncthreads();
        sb[tid] += t;
        __syncthreads();
    }
    bpre[tid] = sb[tid] - v;
    if (tid == 255) bpre[256] = sb[255];
    __syncthreads();
    int tot = (int)bpre[256];
    for (int f = tid; f < tot; f += 256) {
        int lo = 0, hi = 256;
        while (hi - lo > 1) {  // find b: bpre[b] <= f < bpre[b+1]
            int mid = (lo + hi) >> 1;
            if (bpre[mid] <= (unsigned)f) lo = mid; else hi = mid;
        }
        unsigned p = partE[(size_t)g * GSLICE + (unsigned)lo * BCAP + ((unsigned)f - bpre[lo])];
        int dl = (int)(p & 255);
        int s = (int)(p >> GSHIFT);
        unsigned r = atomicAdd(&hist[dl], 1u);
        if (r < MAXDEG)  // statistically unreachable (max deg ~40)
            es[dl * MAXDEG + r] = (unsigned short)s;
    }
    __syncthreads();
    // flush: 256 rows x 128B = 2048 x 16B (eidx padded to ngrp*256 rows)
    const u32x4* s4 = (const u32x4*)es;
    u32x4* d4 = (u32x4*)(eidx + ((size_t)g << GSHIFT) * MAXDEG);
    for (int i = tid; i < 2048; i += 256)
        __builtin_nontemporal_store(s4[i], &d4[i]);
    int node = (g << GSHIFT) + tid;
    if (node < N) cnt[node] = (int)hist[tid];
}

// ---------------- mean aggregation: one wave per dst node, ELL edge table ----------------
// R16-exact gather loop (best measured: 54.3us agg256). CLOSED - do not touch.

template <int D>
__global__ void agg_mean_bf16_kernel(const unsigned short* __restrict__ feat,
                                     const int* __restrict__ cnt,
                                     const unsigned short* __restrict__ eidx,
                                     unsigned short* __restrict__ out, int N) {
    constexpr int VPL = D / 64;  // 2 or 4
    int wave = blockIdx.x * (blockDim.x >> 6) + (threadIdx.x >> 6);
    int lane = threadIdx.x & 63;
    if (wave >= N) return;
    int deg = cnt[wave];
    int stored = deg > MAXDEG ? MAXDEG : deg;
    const unsigned short* row = eidx + (size_t)wave * MAXDEG;
    int myIdx = (lane < stored) ? (int)row[lane] : 0;

    float acc[VPL];
    #pragma unroll
    for (int i = 0; i < VPL; ++i) acc[i] = 0.0f;

    int j = 0;
    for (; j + 8 <= stored; j += 8) {
        if constexpr (VPL == 2) {
            unsigned v[8];
            #pragma unroll
            for (int u = 0; u < 8; ++u) {
                int s = __shfl(myIdx, j + u, 64);
                v[u] = *(const unsigned*)(feat + (size_t)s * D + lane * 2);
            }
            #pragma unroll
            for (int u = 0; u < 8; ++u) { acc[0] += bflo(v[u]); acc[1] += bfhi(v[u]); }
        } else {
            uint2 v[8];
            #pragma unroll
            for (int u = 0; u < 8; ++u) {
                int s = __shfl(myIdx, j + u, 64);
                v[u] = *(const uint2*)(feat + (size_t)s * D + lane * 4);
            }
            #pragma unroll
            for (int u = 0; u < 8; ++u) {
                acc[0] += bflo(v[u].x); acc[1] += bfhi(v[u].x);
                acc[2] += bflo(v[u].y); acc[3] += bfhi(v[u].y);
            }
        }
    }
    for (; j < stored; ++j) {
        int s = __shfl(myIdx, j, 64);
        if constexpr (VPL == 2) {
            unsigned v = *(const unsigned*)(feat + (size_t)s * D + lane * 2);
            acc[0] += bflo(v); acc[1] += bfhi(v);
        } else {
            uint2 v = *(const uint2*)(feat + (size_t)s * D + lane * 4);
            acc[0] += bflo(v.x); acc[1] += bfhi(v.x);
            acc[2] += bflo(v.y); acc[3] += bfhi(v.y);
        }
    }

    float invd = 1.0f / (float)(deg > 0 ? deg : 1);  // true-degree divisor
    if constexpr (VPL == 2) {
        unsigned o = (unsigned)f2bf(acc[0] * invd) | ((unsigned)f2bf(acc[1] * invd) << 16);
        __builtin_nontemporal_store(o, (unsigned*)(out + (size_t)wave * D + lane * 2));
    } else {
        unsigned lo = (unsigned)f2bf(acc[0] * invd) | ((unsigned)f2bf(acc[1] * invd) << 16);
        unsigned hi = (unsigned)f2bf(acc[2] * invd) | ((unsigned)f2bf(acc[3] * invd) << 16);
        unsigned long long o = (unsigned long long)lo | ((unsigned long long)hi << 32);
        __builtin_nontemporal_store(o, (unsigned long long*)(out + (size_t)wave * D + lane * 4));
    }
}

// ---------------- bf16 MFMA GEMM + bias + ReLU ----------------
// MODE 0: store bf16 to Cb; prologue zeroes gsum+done (runs before gemm2).
// MODE 1: fused per-graph-sum epilogue + MERGED HEAD: after done==gridDim.x
// (threadfence+atomic counter; deadlock-free since non-spinners always exit),
// blocks 0..255 atomic-load gsum (XCD-coherent) into LDS and run the MLP head.

template <int K, int MODE>
__launch_bounds__(256)
__global__ void gemm_mfma_kernel(const unsigned short* __restrict__ A,
                                 const unsigned short* __restrict__ Wt,
                                 const float* __restrict__ bias,
                                 unsigned short* __restrict__ Cb,
                                 const int* __restrict__ gids,
                                 float* __restrict__ gsum,
                                 int N, int* __restrict__ done,
                                 const float* __restrict__ Wr1, const float* __restrict__ br1,
                                 const float* __restrict__ Wr2, const float* __restrict__ br2,
                                 const int* __restrict__ gstart, float* __restrict__ out) {
    constexpr int LDS = 40;
    __shared__ unsigned short As[64 * LDS];
    __shared__ unsigned short Bs[256 * LDS];

    int tid = threadIdx.x;
    int wave = tid >> 6;
    int lane = tid & 63;
    int m = lane & 15;
    int q = lane >> 4;
    int rowBase = blockIdx.x * 64;

    if constexpr (MODE == 0) {  // zero gsum + done for gemm2 (dispatch-ordered)
        if (blockIdx.x < NUM_GRAPHS) gsum[blockIdx.x * 256 + tid] = 0.0f;
        if (blockIdx.x == 0 && tid == 0) *done = 0;
    }

    f32x4 acc[4][4] = {};

    for (int kc = 0; kc < K; kc += 32) {
        {
            int r = tid >> 2;
            int seg = tid & 3;
            int gr = rowBase + r;
            uint4 v = make_uint4(0, 0, 0, 0);
            if (gr < N) v = *(const uint4*)(A + (size_t)gr * K + kc + seg * 8);
            *(uint4*)&As[r * LDS + seg * 8] = v;
        }
        #pragma unroll
        for (int it = 0; it < 4; ++it) {
            int n = (tid >> 2) + it * 64;
            int seg = tid & 3;
            uint4 v = *(const uint4*)(Wt + (size_t)n * K + kc + seg * 8);
            *(uint4*)&Bs[n * LDS + seg * 8] = v;
        }
        __syncthreads();

        bf16x8 af[4], bfr[4];
        #pragma unroll
        for (int r = 0; r < 4; ++r)
            af[r] = *(const bf16x8*)&As[(r * 16 + m) * LDS + q * 8];
        #pragma unroll
        for (int c = 0; c < 4; ++c)
            bfr[c] = *(const bf16x8*)&Bs[(wave * 64 + c * 16 + m) * LDS + q * 8];
        #pragma unroll
        for (int r = 0; r < 4; ++r)
            #pragma unroll
            for (int c = 0; c < 4; ++c)
                acc[r][c] = __builtin_amdgcn_mfma_f32_16x16x32_bf16(af[r], bfr[c], acc[r][c], 0, 0, 0);
        __syncthreads();
    }

    if constexpr (MODE == 0) {
        #pragma unroll
        for (int c = 0; c < 4; ++c) {
            int col = wave * 64 + c * 16 + m;
            float bv = bias[col];
            #pragma unroll
            for (int r = 0; r < 4; ++r) {
                #pragma unroll
                for (int reg = 0; reg < 4; ++reg) {
                    int grow = rowBase + r * 16 + q * 4 + reg;
                    if (grow < N)
                        Cb[(size_t)grow * 256 + col] = f2bf(fmaxf(acc[r][c][reg] + bv, 0.0f));
                }
            }
        }
    } else {
        int* sgid = (int*)As;
        if (tid < 64) {
            int gr = rowBase + tid;
            sgid[tid] = (gr < N) ? gids[gr] : 0x7fffffff;
        }
        __syncthreads();
        int lastValid = N - 1 - rowBase;
        if (lastValid > 63) lastValid = 63;
        int gmin = sgid[0];
        int gmax = sgid[lastValid];
        #pragma unroll
        for (int c = 0; c < 4; ++c) {
            int col = wave * 64 + c * 16 + m;
            float bv = bias[col];
            for (int g = gmin; g <= gmax; ++g) {
                float p = 0.0f;
                #pragma unroll
                for (int r = 0; r < 4; ++r) {
                    #pragma unroll
                    for (int reg = 0; reg < 4; ++reg) {
                        int lr = r * 16 + q * 4 + reg;
                        if (sgid[lr] == g)
                            p += fmaxf(acc[r][c][reg] + bv, 0.0f);
                    }
                }
                p += __shfl_xor(p, 16, 64);
                p += __shfl_xor(p, 32, 64);
                if (q == 0 && p != 0.0f)
                    atomicAdd(&gsum[g * 256 + col], p);
            }
        }
        // ---- merged MLP head ----
        __threadfence();
        if (tid == 0) atomicAdd(done, 1);
        if (blockIdx.x < NUM_GRAPHS) {
            __shared__ float sgs[256];
            __shared__ float part[256];
            __shared__ float ws2h[2];
            if (tid == 0) {
                while (atomicAdd(done, 0) < (int)gridDim.x) {}
            }
            __syncthreads();
            int g = blockIdx.x;
            sgs[tid] = atomicAdd(&gsum[g * 256 + tid], 0.0f);  // coherent read
            __syncthreads();
            int c = gstart[g + 1] - gstart[g];
            float invc = 1.0f / (float)(c > 0 ? c : 1);
            int j = tid & 127;
            int kq = tid >> 7;
            float acch = 0.0f;
            #pragma unroll 8
            for (int k = kq * 128; k < kq * 128 + 128; ++k)
                acch += sgs[k] * Wr1[k * 128 + j];
            part[tid] = acch;
            __syncthreads();
            if (tid < 128) {
                float s2 = part[j] + part[128 + j];
                float p = (s2 * invc + br1[j]) * Wr2[j];
                #pragma unroll
                for (int d = 32; d > 0; d >>= 1) p += __shfl_down(p, d, 64);
                if ((tid & 63) == 0) ws2h[tid >> 6] = p;
            }
            __syncthreads();
            if (tid == 0) out[g] = ws2h[0] + ws2h[1] + br2[0];
        }
    }
}

// ---------------- launch ----------------

extern "C" void kernel_launch(void* const* d_in, const int* in_sizes, int n_in,
                              void* d_out, int out_size, void* d_ws, size_t ws_size,
                              hipStream_t stream) {
    const float* h    = (const float*)d_in[0];
    const int*   src  = (const int*)d_in[1];
    const int*   dst  = (const int*)d_in[2];
    const int*   gids = (const int*)d_in[3];
    const float* W1   = (const float*)d_in[4];
    const float* b1   = (const float*)d_in[5];
    const float* W2   = (const float*)d_in[6];
    const float* b2   = (const float*)d_in[7];
    const float* Wr1  = (const float*)d_in[8];
    const float* br1  = (const float*)d_in[9];
    const float* Wr2  = (const float*)d_in[10];
    const float* br2  = (const float*)d_in[11];

    int N = in_sizes[0] / 128;
    int E = in_sizes[1];
    int ngrp = (N + 255) >> GSHIFT;  // 196 for N=50000 (must be <= 256)

    // workspace
    char* w = (char*)d_ws;
    unsigned short* hb     = (unsigned short*)w;  w += (size_t)N * 128 * sizeof(unsigned short);
    unsigned short* h1b    = (unsigned short*)w;  w += (size_t)N * 256 * sizeof(unsigned short);
    unsigned short* aggOut = (unsigned short*)w;  w += (size_t)N * 256 * sizeof(unsigned short);
    int* cnt    = (int*)w;              w += (size_t)N * sizeof(int);
    float* gsum = (float*)w;            w += (size_t)NUM_GRAPHS * 256 * sizeof(float);
    int* done   = (int*)w;              w += 16;
    int* bcnt   = (int*)w;              w += 256 * 256 * sizeof(int);
    unsigned short* eidx = (unsigned short*)w;  w += (size_t)ngrp * 256 * MAXDEG * sizeof(unsigned short);
    unsigned short* Wt1 = (unsigned short*)w;   w += 256 * 128 * sizeof(unsigned short);
    unsigned short* Wt2 = (unsigned short*)w;   w += 256 * 256 * sizeof(unsigned short);
    int* gstart = (int*)w;              w += (size_t)(NUM_GRAPHS + 1) * sizeof(int);
    // partE aliases aggOut: partE live = dispatches 1-2, aggOut live from 3 on.
    // (256 groups x GSLICE x 4B = 12.6MB < 25.6MB)
    unsigned* partE = (unsigned*)aggOut;

    // 1) prep: fixed-slice edge partition, gstart, h cast, weight transposes
    //    (no memset: bcnt fully written; gsum/done zeroed inside gemm1)
    misc_kernel<<<MISC_NB, 256, 0, stream>>>(dst, src, gids, h, W1, W2, bcnt, partE,
                                             gstart, hb, Wt1, Wt2, N, E);
    // 2) ELL build: LDS-staged tile, fully-coalesced global writes
    build_kernel<<<ngrp, 256, 0, stream>>>(partE, bcnt, cnt, eidx, N);

    // 3-4) layer 1 (gemm1 prologue zeroes gsum+done for gemm2)
    agg_mean_bf16_kernel<128><<<(N + 3) / 4, 256, 0, stream>>>(hb, cnt, eidx, aggOut, N);
    gemm_mfma_kernel<128, 0><<<(N + 63) / 64, 256, 0, stream>>>(
        aggOut, Wt1, b1, h1b, nullptr, gsum, N, done,
        nullptr, nullptr, nullptr, nullptr, nullptr, nullptr);

    // 5-6) layer 2 (readout + MLP head fused into gemm2)
    agg_mean_bf16_kernel<256><<<(N + 3) / 4, 256, 0, stream>>>(h1b, cnt, eidx, aggOut, N);
    gemm_mfma_kernel<256, 1><<<(N + 63) / 64, 256, 0, stream>>>(
        aggOut, Wt2, b2, nullptr, gids, gsum, N, done,
        Wr1, br1, Wr2, br2, gstart, (float*)d_out);
}

// Round 12
// 285.565 us; speedup vs baseline: 1.3855x; 1.3855x over previous
//
#include <hip/hip_runtime.h>

// GCN regressor: 2x (mean-aggregate + linear+ReLU) + per-graph mean + MLP head.
// N=50000 nodes, E=800000 edges, D_IN=128, H1=256, H2=128, G=256.
// R26 = R24 + validated-safe half of R25, toxic half reverted:
//  - memset dispatch DELETED (bcnt fixed-slice partition, R25-verified correct;
//    gsum zeroed in gemm1 prologue - dispatch-ordered before gemm2 atomics)
//  - final_kernel RESTORED as own dispatch (R25 spin merge: gemm2 12->140us,
//    occupancy 19%, spinners parked on CU slots hammering one coherence line.
//    In-kernel all-blocks waits are CLOSED: R8/R9 cooperative 2x, R25 spin 2.5x)
//  - gstart + weight transposes moved misc -> build grid (build used 196/256
//    CUs; these 112 independent blocks fill idle CUs, shrink misc)
//  8 -> 7 dispatches, zero added sync. Clean boundary-cost readout:
//  >=277 -> gaps cheap, probe middle dispatches next; <=265 -> keep merging.
// AGG MODEL CLOSED (quantitative): ~11 cyc per 128B line per CU at L1/TA.
//  agg256 = 800K instr x 4 lines = 3.2M lines -> 54.6us predicted, 54.3
//  measured. R16 hoist -2.6; R17/R18 economy null; R19 width-split 11 cyc/line
//  consistent. Hardware floor at D=256 bf16. Do not touch the gather.
// Closed: R6 chunk-gather 7x; R8/R9 grid.sync; R11 agg-GEMM fusion; R13
//  lookback merge; R17 launch_bounds spill; R20 per-edge global atomics;
//  R21/R22 scattered 4B writes (~30us/800K invariant); R25 spin barrier.

#define NUM_GRAPHS 256
#define MAXDEG 64
#define GSHIFT 8              // 256-node groups
#define BCAP 48               // per-(block,group) slice cap (mean 15.9 + 8sig)
#define GSLICE (256 * BCAP)   // entries per group region (12288)
#define CHUNK_MAX 3200        // per-block edge chunk cap (E=800000/256 = 3125)

// misc_kernel block partition (partition + cast only)
#define PART_B0 0
#define PART_NB 256
#define CST_B0 (PART_B0 + PART_NB)
#define CST_NB 512
#define MISC_NB (CST_B0 + CST_NB)

// build_kernel extra sections (after ngrp build blocks)
#define GST_NB 64
#define WT1_NB 16
#define WT2_NB 32

typedef __attribute__((ext_vector_type(8))) short bf16x8;
typedef __attribute__((ext_vector_type(4))) float f32x4;
typedef __attribute__((ext_vector_type(4))) unsigned int u32x4;

__device__ inline unsigned short f2bf(float f) {  // round-to-nearest-even
    unsigned u = __float_as_uint(f);
    return (unsigned short)((u + 0x7fff + ((u >> 16) & 1)) >> 16);
}
__device__ inline float bflo(unsigned u) { return __uint_as_float(u << 16); }
__device__ inline float bfhi(unsigned u) { return __uint_as_float(u & 0xffff0000u); }

// ---------------- misc: edge partition (fixed slices) + h cast ----------------

__launch_bounds__(256)
__global__ void misc_kernel(const int* __restrict__ dst, const int* __restrict__ src,
                            const float* __restrict__ h,
                            int* __restrict__ bcnt, unsigned* __restrict__ partE,
                            unsigned short* __restrict__ hb,
                            int N, int E) {
    int b = blockIdx.x, tid = threadIdx.x;
    if (b < CST_B0) {  // partition: hist -> scan -> LDS compaction -> coalesced flush
        __shared__ unsigned lcnt[256];
        __shared__ unsigned sbuf[256];
        __shared__ unsigned lbase[257];
        __shared__ unsigned comp[CHUNK_MAX];
        int b0 = b - PART_B0;
        int chunk = (E + PART_NB - 1) / PART_NB;
        int ebeg = b0 * chunk;
        int eend = ebeg + chunk; if (eend > E) eend = E;
        int ecount = eend - ebeg; if (ecount < 0) ecount = 0;

        lcnt[tid] = 0;
        __syncthreads();
        for (int e = ebeg + tid; e < eend; e += 256) {
            int d = __builtin_nontemporal_load(&dst[e]);
            atomicAdd(&lcnt[d >> GSHIFT], 1u);
        }
        __syncthreads();
        // Kogge-Stone inclusive scan over 256 bins -> exclusive lbase
        unsigned v = lcnt[tid];
        sbuf[tid] = v;
        __syncthreads();
        #pragma unroll
        for (int dd = 1; dd < 256; dd <<= 1) {
            unsigned t = (tid >= dd) ? sbuf[tid - dd] : 0u;
            __syncthreads();
            sbuf[tid] += t;
            __syncthreads();
        }
        lbase[tid] = sbuf[tid] - v;
        if (tid == 255) lbase[256] = sbuf[255];
        // publish per-(block,group) count (coalesced, no atomics, no memset)
        bcnt[b0 * 256 + tid] = (int)(v < BCAP ? v : BCAP);
        lcnt[tid] = 0;
        __syncthreads();
        // sweep 2: LDS scatter into group-ordered compacted buffer
        for (int e = ebeg + tid; e < eend; e += 256) {
            int d = __builtin_nontemporal_load(&dst[e]);
            int s = __builtin_nontemporal_load(&src[e]);
            int g = d >> GSHIFT;
            unsigned r = atomicAdd(&lcnt[g], 1u) + lbase[g];
            if (r < (unsigned)CHUNK_MAX)  // always true for E=800000
                comp[r] = ((unsigned)s << GSHIFT) | (unsigned)(d & 255);
        }
        __syncthreads();
        // coalesced flush into fixed slice: partE[g*GSLICE + b0*BCAP + off]
        for (int i = tid; i < ecount; i += 256) {
            int lo = 0, hi = 256;
            while (hi - lo > 1) {  // find g: lbase[g] <= i < lbase[g+1]
                int mid = (lo + hi) >> 1;
                if (lbase[mid] <= (unsigned)i) lo = mid; else hi = mid;
            }
            unsigned off = (unsigned)i - lbase[lo];
            if (off < (unsigned)BCAP)  // statistically unreachable guard
                __builtin_nontemporal_store(
                    comp[i], &partE[(size_t)lo * GSLICE + (unsigned)b0 * BCAP + off]);
        }
    } else {  // cast h -> bf16 (float4 granules)
        int lid = (b - CST_B0) * 256 + tid;
        int total4 = N * 32;
        for (int i = lid; i < total4; i += CST_NB * 256) {
            float4 v = *(const float4*)(h + (size_t)i * 4);
            ushort4 o;
            o.x = f2bf(v.x); o.y = f2bf(v.y); o.z = f2bf(v.z); o.w = f2bf(v.w);
            *(ushort4*)(hb + (size_t)i * 4) = o;
        }
    }
}

// ---------------- build: ELL tiles in LDS + gstart + weight transposes ----------------
// Blocks [0,ngrp): per-group ELL build (rank scatter LDS-local, u32x4 flush).
// Blocks [ngrp, ngrp+112): gstart + Wt1 + Wt2 (independent; fill idle CUs).

__launch_bounds__(256)
__global__ void build_kernel(const unsigned* __restrict__ partE,
                             const int* __restrict__ bcnt,
                             int* __restrict__ cnt, unsigned short* __restrict__ eidx,
                             const int* __restrict__ gids, int* __restrict__ gstart,
                             const float* __restrict__ W1, const float* __restrict__ W2,
                             unsigned short* __restrict__ Wt1, unsigned short* __restrict__ Wt2,
                             int N, int ngrp) {
    __shared__ unsigned short es[256 * MAXDEG];  // 32KB ELL tile
    __shared__ unsigned hist[256];
    __shared__ unsigned sb[256];
    __shared__ unsigned bpre[257];
    int b = blockIdx.x, tid = threadIdx.x;
    if (b < ngrp) {
        int g = b;
        hist[tid] = 0;
        unsigned v = (unsigned)bcnt[tid * 256 + g];  // block tid's count for group g
        sb[tid] = v;
        __syncthreads();
        #pragma unroll
        for (int dd = 1; dd < 256; dd <<= 1) {
            unsigned t = (tid >= dd) ? sb[tid - dd] : 0u;
            __syncthreads();
            sb[tid] += t;
            __syncthreads();
        }
        bpre[tid] = sb[tid] - v;
        if (tid == 255) bpre[256] = sb[255];
        __syncthreads();
        int tot = (int)bpre[256];
        for (int f = tid; f < tot; f += 256) {
            int lo = 0, hi = 256;
            while (hi - lo > 1) {  // find b: bpre[b] <= f < bpre[b+1]
                int mid = (lo + hi) >> 1;
                if (bpre[mid] <= (unsigned)f) lo = mid; else hi = mid;
            }
            unsigned p = partE[(size_t)g * GSLICE + (unsigned)lo * BCAP + ((unsigned)f - bpre[lo])];
            int dl = (int)(p & 255);
            int s = (int)(p >> GSHIFT);
            unsigned r = atomicAdd(&hist[dl], 1u);
            if (r < MAXDEG)  // statistically unreachable (max deg ~40)
                es[dl * MAXDEG + r] = (unsigned short)s;
        }
        __syncthreads();
        // flush: 256 rows x 128B = 2048 x 16B (eidx padded to ngrp*256 rows)
        const u32x4* s4 = (const u32x4*)es;
        u32x4* d4 = (u32x4*)(eidx + ((size_t)g << GSHIFT) * MAXDEG);
        for (int i = tid; i < 2048; i += 256)
            __builtin_nontemporal_store(s4[i], &d4[i]);
        int node = (g << GSHIFT) + tid;
        if (node < N) cnt[node] = (int)hist[tid];
    } else {
        int bb = b - ngrp;
        if (bb < GST_NB) {  // graph segment starts (gids sorted)
            int lid = bb * 256 + tid;
            for (int n = lid; n < N; n += GST_NB * 256) {
                int g = gids[n];
                int gp = (n == 0) ? -1 : gids[n - 1];
                for (int x = gp + 1; x <= g; ++x) gstart[x] = n;
                if (n == N - 1)
                    for (int x = g + 1; x <= NUM_GRAPHS; ++x) gstart[x] = N;
            }
        } else if (bb < GST_NB + WT1_NB) {  // Wt1[n][k] = bf16(W1[k][n]), K=128
            int lid = (bb - GST_NB) * 256 + tid;
            for (int i = lid; i < 256 * 128; i += WT1_NB * 256)
                Wt1[i] = f2bf(W1[(size_t)(i & 127) * 256 + (i >> 7)]);
        } else {  // Wt2[n][k] = bf16(W2[k][n]), K=256
            int lid = (bb - GST_NB - WT1_NB) * 256 + tid;
            for (int i = lid; i < 256 * 256; i += WT2_NB * 256)
                Wt2[i] = f2bf(W2[(size_t)(i & 255) * 256 + (i >> 8)]);
        }
    }
}

// ---------------- mean aggregation: one wave per dst node, ELL edge table ----------------
// CLOSED at the ~11 cyc/128B-line/CU service floor (54.3us = 3.2M lines).

template <int D>
__global__ void agg_mean_bf16_kernel(const unsigned short* __restrict__ feat,
                                     const int* __restrict__ cnt,
                                     const unsigned short* __restrict__ eidx,
                                     unsigned short* __restrict__ out, int N) {
    constexpr int VPL = D / 64;  // 2 or 4
    int wave = blockIdx.x * (blockDim.x >> 6) + (threadIdx.x >> 6);
    int lane = threadIdx.x & 63;
    if (wave >= N) return;
    int deg = cnt[wave];
    int stored = deg > MAXDEG ? MAXDEG : deg;
    const unsigned short* row = eidx + (size_t)wave * MAXDEG;
    int myIdx = (lane < stored) ? (int)row[lane] : 0;

    float acc[VPL];
    #pragma unroll
    for (int i = 0; i < VPL; ++i) acc[i] = 0.0f;

    int j = 0;
    for (; j + 8 <= stored; j += 8) {
        if constexpr (VPL == 2) {
            unsigned v[8];
            #pragma unroll
            for (int u = 0; u < 8; ++u) {
                int s = __shfl(myIdx, j + u, 64);
                v[u] = *(const unsigned*)(feat + (size_t)s * D + lane * 2);
            }
            #pragma unroll
            for (int u = 0; u < 8; ++u) { acc[0] += bflo(v[u]); acc[1] += bfhi(v[u]); }
        } else {
            uint2 v[8];
            #pragma unroll
            for (int u = 0; u < 8; ++u) {
                int s = __shfl(myIdx, j + u, 64);
                v[u] = *(const uint2*)(feat + (size_t)s * D + lane * 4);
            }
            #pragma unroll
            for (int u = 0; u < 8; ++u) {
                acc[0] += bflo(v[u].x); acc[1] += bfhi(v[u].x);
                acc[2] += bflo(v[u].y); acc[3] += bfhi(v[u].y);
            }
        }
    }
    for (; j < stored; ++j) {
        int s = __shfl(myIdx, j, 64);
        if constexpr (VPL == 2) {
            unsigned v = *(const unsigned*)(feat + (size_t)s * D + lane * 2);
            acc[0] += bflo(v); acc[1] += bfhi(v);
        } else {
            uint2 v = *(const uint2*)(feat + (size_t)s * D + lane * 4);
            acc[0] += bflo(v.x); acc[1] += bfhi(v.x);
            acc[2] += bflo(v.y); acc[3] += bfhi(v.y);
        }
    }

    float invd = 1.0f / (float)(deg > 0 ? deg : 1);  // true-degree divisor
    if constexpr (VPL == 2) {
        unsigned o = (unsigned)f2bf(acc[0] * invd) | ((unsigned)f2bf(acc[1] * invd) << 16);
        __builtin_nontemporal_store(o, (unsigned*)(out + (size_t)wave * D + lane * 2));
    } else {
        unsigned lo = (unsigned)f2bf(acc[0] * invd) | ((unsigned)f2bf(acc[1] * invd) << 16);
        unsigned hi = (unsigned)f2bf(acc[2] * invd) | ((unsigned)f2bf(acc[3] * invd) << 16);
        unsigned long long o = (unsigned long long)lo | ((unsigned long long)hi << 32);
        __builtin_nontemporal_store(o, (unsigned long long*)(out + (size_t)wave * D + lane * 4));
    }
}

// ---------------- bf16 MFMA GEMM + bias + ReLU ----------------
// MODE 0: store bf16 to Cb; prologue zeroes gsum (dispatch-ordered before
// gemm2's atomics). MODE 1: fused per-graph-sum epilogue (shfl-reduced,
// one atomicAdd per (col,graph) per block).

template <int K, int MODE>
__launch_bounds__(256)
__global__ void gemm_mfma_kernel(const unsigned short* __restrict__ A,
                                 const unsigned short* __restrict__ Wt,
                                 const float* __restrict__ bias,
                                 unsigned short* __restrict__ Cb,
                                 const int* __restrict__ gids,
                                 float* __restrict__ gsum,
                                 int N) {
    constexpr int LDS = 40;
    __shared__ unsigned short As[64 * LDS];
    __shared__ unsigned short Bs[256 * LDS];

    int tid = threadIdx.x;
    int wave = tid >> 6;
    int lane = tid & 63;
    int m = lane & 15;
    int q = lane >> 4;
    int rowBase = blockIdx.x * 64;

    if constexpr (MODE == 0) {  // zero gsum for gemm2 (dispatch-ordered)
        if (blockIdx.x < NUM_GRAPHS) gsum[blockIdx.x * 256 + tid] = 0.0f;
    }

    f32x4 acc[4][4] = {};

    for (int kc = 0; kc < K; kc += 32) {
        {
            int r = tid >> 2;
            int seg = tid & 3;
            int gr = rowBase + r;
            uint4 v = make_uint4(0, 0, 0, 0);
            if (gr < N) v = *(const uint4*)(A + (size_t)gr * K + kc + seg * 8);
            *(uint4*)&As[r * LDS + seg * 8] = v;
        }
        #pragma unroll
        for (int it = 0; it < 4; ++it) {
            int n = (tid >> 2) + it * 64;
            int seg = tid & 3;
            uint4 v = *(const uint4*)(Wt + (size_t)n * K + kc + seg * 8);
            *(uint4*)&Bs[n * LDS + seg * 8] = v;
        }
        __syncthreads();

        bf16x8 af[4], bfr[4];
        #pragma unroll
        for (int r = 0; r < 4; ++r)
            af[r] = *(const bf16x8*)&As[(r * 16 + m) * LDS + q * 8];
        #pragma unroll
        for (int c = 0; c < 4; ++c)
            bfr[c] = *(const bf16x8*)&Bs[(wave * 64 + c * 16 + m) * LDS + q * 8];
        #pragma unroll
        for (int r = 0; r < 4; ++r)
            #pragma unroll
            for (int c = 0; c < 4; ++c)
                acc[r][c] = __builtin_amdgcn_mfma_f32_16x16x32_bf16(af[r], bfr[c], acc[r][c], 0, 0, 0);
        __syncthreads();
    }

    if constexpr (MODE == 0) {
        #pragma unroll
        for (int c = 0; c < 4; ++c) {
            int col = wave * 64 + c * 16 + m;
            float bv = bias[col];
            #pragma unroll
            for (int r = 0; r < 4; ++r) {
                #pragma unroll
                for (int reg = 0; reg < 4; ++reg) {
                    int grow = rowBase + r * 16 + q * 4 + reg;
                    if (grow < N)
                        Cb[(size_t)grow * 256 + col] = f2bf(fmaxf(acc[r][c][reg] + bv, 0.0f));
                }
            }
        }
    } else {
        int* sgid = (int*)As;
        if (tid < 64) {
            int gr = rowBase + tid;
            sgid[tid] = (gr < N) ? gids[gr] : 0x7fffffff;
        }
        __syncthreads();
        int lastValid = N - 1 - rowBase;
        if (lastValid > 63) lastValid = 63;
        int gmin = sgid[0];
        int gmax = sgid[lastValid];
        #pragma unroll
        for (int c = 0; c < 4; ++c) {
            int col = wave * 64 + c * 16 + m;
            float bv = bias[col];
            for (int g = gmin; g <= gmax; ++g) {
                float p = 0.0f;
                #pragma unroll
                for (int r = 0; r < 4; ++r) {
                    #pragma unroll
                    for (int reg = 0; reg < 4; ++reg) {
                        int lr = r * 16 + q * 4 + reg;
                        if (sgid[lr] == g)
                            p += fmaxf(acc[r][c][reg] + bv, 0.0f);
                    }
                }
                p += __shfl_xor(p, 16, 64);
                p += __shfl_xor(p, 32, 64);
                if (q == 0 && p != 0.0f)
                    atomicAdd(&gsum[g * 256 + col], p);
            }
        }
    }
}

// ---------------- MLP head ----------------
// 512 threads: 4-way k-split (j = t&127, kq = t>>7 handles 64 ks) + LDS
// combine. 8 waves/CU: the 64-deep Wr1 load chain gets hidden.

__global__ void final_kernel(const float* __restrict__ gsum, const int* __restrict__ gstart,
                             const float* __restrict__ Wr1, const float* __restrict__ br1,
                             const float* __restrict__ Wr2, const float* __restrict__ br2,
                             float* __restrict__ out) {
    __shared__ float part[512];
    __shared__ float ws2[2];
    int g = blockIdx.x;
    int t = threadIdx.x;  // 512
    int j = t & 127;
    int kq = t >> 7;
    int c = gstart[g + 1] - gstart[g];
    float invc = 1.0f / (float)(c > 0 ? c : 1);
    const float* gs = gsum + g * 256;
    float acc = 0.0f;
    #pragma unroll 8
    for (int k = kq * 64; k < kq * 64 + 64; ++k)
        acc += gs[k] * Wr1[k * 128 + j];
    part[t] = acc;
    __syncthreads();
    if (t < 128) {
        float s = part[j] + part[128 + j] + part[256 + j] + part[384 + j];
        float p = (s * invc + br1[j]) * Wr2[j];
        #pragma unroll
        for (int d = 32; d > 0; d >>= 1) p += __shfl_down(p, d, 64);
        if ((t & 63) == 0) ws2[t >> 6] = p;
    }
    __syncthreads();
    if (t == 0) out[g] = ws2[0] + ws2[1] + br2[0];
}

// ---------------- launch ----------------

extern "C" void kernel_launch(void* const* d_in, const int* in_sizes, int n_in,
                              void* d_out, int out_size, void* d_ws, size_t ws_size,
                              hipStream_t stream) {
    const float* h    = (const float*)d_in[0];
    const int*   src  = (const int*)d_in[1];
    const int*   dst  = (const int*)d_in[2];
    const int*   gids = (const int*)d_in[3];
    const float* W1   = (const float*)d_in[4];
    const float* b1   = (const float*)d_in[5];
    const float* W2   = (const float*)d_in[6];
    const float* b2   = (const float*)d_in[7];
    const float* Wr1  = (const float*)d_in[8];
    const float* br1  = (const float*)d_in[9];
    const float* Wr2  = (const float*)d_in[10];
    const float* br2  = (const float*)d_in[11];

    int N = in_sizes[0] / 128;
    int E = in_sizes[1];
    int ngrp = (N + 255) >> GSHIFT;  // 196 for N=50000 (must be <= 256)

    // workspace
    char* w = (char*)d_ws;
    unsigned short* hb     = (unsigned short*)w;  w += (size_t)N * 128 * sizeof(unsigned short);
    unsigned short* h1b    = (unsigned short*)w;  w += (size_t)N * 256 * sizeof(unsigned short);
    unsigned short* aggOut = (unsigned short*)w;  w += (size_t)N * 256 * sizeof(unsigned short);
    int* cnt    = (int*)w;              w += (size_t)N * sizeof(int);
    float* gsum = (float*)w;            w += (size_t)NUM_GRAPHS * 256 * sizeof(float);
    int* bcnt   = (int*)w;              w += 256 * 256 * sizeof(int);
    unsigned short* eidx = (unsigned short*)w;  w += (size_t)ngrp * 256 * MAXDEG * sizeof(unsigned short);
    unsigned short* Wt1 = (unsigned short*)w;   w += 256 * 128 * sizeof(unsigned short);
    unsigned short* Wt2 = (unsigned short*)w;   w += 256 * 256 * sizeof(unsigned short);
    int* gstart = (int*)w;              w += (size_t)(NUM_GRAPHS + 1) * sizeof(int);
    // partE aliases aggOut: partE live = dispatches 1-2, aggOut live from 3 on.
    // (256 groups x GSLICE x 4B = 12.6MB < 25.6MB)
    unsigned* partE = (unsigned*)aggOut;

    // 1) prep: fixed-slice edge partition + h cast (no memset anywhere)
    misc_kernel<<<MISC_NB, 256, 0, stream>>>(dst, src, h, bcnt, partE, hb, N, E);
    // 2) ELL build (LDS tile, coalesced flush) + gstart + weight transposes
    build_kernel<<<ngrp + GST_NB + WT1_NB + WT2_NB, 256, 0, stream>>>(
        partE, bcnt, cnt, eidx, gids, gstart, W1, W2, Wt1, Wt2, N, ngrp);

    // 3-4) layer 1 (gemm1 prologue zeroes gsum for gemm2)
    agg_mean_bf16_kernel<128><<<(N + 3) / 4, 256, 0, stream>>>(hb, cnt, eidx, aggOut, N);
    gemm_mfma_kernel<128, 0><<<(N + 63) / 64, 256, 0, stream>>>(aggOut, Wt1, b1, h1b, nullptr, gsum, N);

    // 5-6) layer 2 (readout fused into GEMM epilogue)
    agg_mean_bf16_kernel<256><<<(N + 3) / 4, 256, 0, stream>>>(h1b, cnt, eidx, aggOut, N);
    gemm_mfma_kernel<256, 1><<<(N + 63) / 64, 256, 0, stream>>>(aggOut, Wt2, b2, nullptr, gids, gsum, N);

    // 7) head
    final_kernel<<<NUM_GRAPHS, 512, 0, stream>>>(gsum, gstart, Wr1, br1, Wr2, br2, (float*)d_out);
}

// Round 13
// 284.261 us; speedup vs baseline: 1.3919x; 1.0046x over previous
//
#include <hip/hip_runtime.h>

// GCN regressor: 2x (mean-aggregate + linear+ReLU) + per-graph mean + MLP head.
// N=50000 nodes, E=800000 edges, D_IN=128, H1=256, H2=128, G=256.
// R27 = R24 (best measured, 279.6us) + agg256 SPLIT into two node-range halves.
// Purpose: the top-5 table only ever shows 5 iteration-copies of the argmax
// dispatch (agg256, 54us). Splitting it (~28us/half, line-service-bound so
// ~neutral) reveals the true #2 kernel with counters - the first direct
// observation of the middle pipeline after 6 rounds of blind work (net -4us).
// Pre-committed readouts: misc visible -> attack partition; gemm2 -> epilogue;
// build -> flatten; only ~28us agg halves -> all middles <=28, evaluate floor.
// R26 lesson: 8->7 dispatch merge was NEUTRAL-to-negative => boundaries are
// cheap under graph capture; R25's gap inference was wrong.
// AGG MODEL (quantitative, closed): ~11 cyc per 128B line per CU.
//  agg256 3.2M lines -> 54.6 pred / 54.3 meas. R19 half-width: 3.2M lines ->
//  58 meas. agg128 1.6M lines -> ~28 (inferred, never directly seen).
// Closed: R6 chunk-gather 7x; R8/R9 grid.sync 2x; R11 agg-GEMM fusion; R13
//  lookback merge; R16-R19 gather probes (chain/economy/width: floor); R17
//  launch_bounds spill; R20 per-edge global atomics; R21/R22 scattered 4B
//  writes (~30us/800K invariant); R25 spin barrier (140us); R26 merge.

#define NUM_GRAPHS 256
#define MAXDEG 64
#define GSHIFT 8              // 256-node groups
#define GCAP 4864             // per-group edge capacity (mean 4082, +12 sigma)
#define CHUNK_MAX 3200        // per-block edge chunk cap (E=800000/256 = 3125)

// misc_kernel block partition
#define PART_B0 0
#define PART_NB 256
#define CST_B0 (PART_B0 + PART_NB)
#define CST_NB 512
#define GST_B0 (CST_B0 + CST_NB)
#define GST_NB 64
#define WT1_B0 (GST_B0 + GST_NB)
#define WT1_NB 16
#define WT2_B0 (WT1_B0 + WT1_NB)
#define WT2_NB 32
#define MISC_NB (WT2_B0 + WT2_NB)

typedef __attribute__((ext_vector_type(8))) short bf16x8;
typedef __attribute__((ext_vector_type(4))) float f32x4;
typedef __attribute__((ext_vector_type(4))) unsigned int u32x4;

__device__ inline unsigned short f2bf(float f) {  // round-to-nearest-even
    unsigned u = __float_as_uint(f);
    return (unsigned short)((u + 0x7fff + ((u >> 16) & 1)) >> 16);
}
__device__ inline float bflo(unsigned u) { return __uint_as_float(u << 16); }
__device__ inline float bfhi(unsigned u) { return __uint_as_float(u & 0xffff0000u); }

// ---------------- misc: edge partition (compacted) + gstart + h cast + weight transposes ----------------

__launch_bounds__(256)
__global__ void misc_kernel(const int* __restrict__ dst, const int* __restrict__ src,
                            const int* __restrict__ gids,
                            const float* __restrict__ h,
                            const float* __restrict__ W1, const float* __restrict__ W2,
                            int* __restrict__ cursor, unsigned* __restrict__ partE,
                            int* __restrict__ gstart,
                            unsigned short* __restrict__ hb,
                            unsigned short* __restrict__ Wt1, unsigned short* __restrict__ Wt2,
                            int N, int E) {
    int b = blockIdx.x, tid = threadIdx.x;
    if (b < CST_B0) {  // partition: hist -> scan -> LDS compaction -> coalesced flush
        __shared__ unsigned lcnt[256];
        __shared__ unsigned sbuf[256];
        __shared__ unsigned lbase[257];
        __shared__ unsigned gb[256];
        __shared__ unsigned comp[CHUNK_MAX];
        int b0 = b - PART_B0;
        int chunk = (E + PART_NB - 1) / PART_NB;
        int ebeg = b0 * chunk;
        int eend = ebeg + chunk; if (eend > E) eend = E;
        int ecount = eend - ebeg; if (ecount < 0) ecount = 0;

        lcnt[tid] = 0;
        __syncthreads();
        for (int e = ebeg + tid; e < eend; e += 256) {
            int d = __builtin_nontemporal_load(&dst[e]);
            atomicAdd(&lcnt[d >> GSHIFT], 1u);
        }
        __syncthreads();
        // Kogge-Stone inclusive scan over 256 bins -> exclusive lbase
        unsigned v = lcnt[tid];
        sbuf[tid] = v;
        __syncthreads();
        #pragma unroll
        for (int dd = 1; dd < 256; dd <<= 1) {
            unsigned t = (tid >= dd) ? sbuf[tid - dd] : 0u;
            __syncthreads();
            sbuf[tid] += t;
            __syncthreads();
        }
        lbase[tid] = sbuf[tid] - v;
        if (tid == 255) lbase[256] = sbuf[255];
        // claim global run per non-empty group; reset lcnt for sweep 2
        gb[tid] = v ? (unsigned)atomicAdd(&cursor[tid], (int)v) : 0u;
        lcnt[tid] = 0;
        __syncthreads();
        // sweep 2: LDS scatter into group-ordered compacted buffer
        for (int e = ebeg + tid; e < eend; e += 256) {
            int d = __builtin_nontemporal_load(&dst[e]);
            int s = __builtin_nontemporal_load(&src[e]);
            int g = d >> GSHIFT;
            unsigned r = atomicAdd(&lcnt[g], 1u) + lbase[g];
            if (r < (unsigned)CHUNK_MAX)  // always true for E=800000
                comp[r] = ((unsigned)s << GSHIFT) | (unsigned)(d & 255);
        }
        __syncthreads();
        // coalesced flush: consecutive i in a run -> consecutive global addrs
        for (int i = tid; i < ecount; i += 256) {
            int lo = 0, hi = 256;
            while (hi - lo > 1) {  // find g: lbase[g] <= i < lbase[g+1]
                int mid = (lo + hi) >> 1;
                if (lbase[mid] <= (unsigned)i) lo = mid; else hi = mid;
            }
            unsigned dest = (unsigned)lo * GCAP + gb[lo] + ((unsigned)i - lbase[lo]);
            if (dest < (unsigned)(256 * GCAP))
                __builtin_nontemporal_store(comp[i], &partE[dest]);
        }
    } else if (b < GST_B0) {  // cast h -> bf16 (float4 granules)
        int lid = (b - CST_B0) * 256 + tid;
        int total4 = N * 32;
        for (int i = lid; i < total4; i += CST_NB * 256) {
            float4 v = *(const float4*)(h + (size_t)i * 4);
            ushort4 o;
            o.x = f2bf(v.x); o.y = f2bf(v.y); o.z = f2bf(v.z); o.w = f2bf(v.w);
            *(ushort4*)(hb + (size_t)i * 4) = o;
        }
    } else if (b < WT1_B0) {  // graph segment starts (gids sorted)
        int lid = (b - GST_B0) * 256 + tid;
        for (int n = lid; n < N; n += GST_NB * 256) {
            int g = gids[n];
            int gp = (n == 0) ? -1 : gids[n - 1];
            for (int x = gp + 1; x <= g; ++x) gstart[x] = n;
            if (n == N - 1)
                for (int x = g + 1; x <= NUM_GRAPHS; ++x) gstart[x] = N;
        }
    } else if (b < WT2_B0) {  // Wt1[n][k] = bf16(W1[k][n]), K=128
        int lid = (b - WT1_B0) * 256 + tid;
        for (int i = lid; i < 256 * 128; i += WT1_NB * 256)
            Wt1[i] = f2bf(W1[(size_t)(i & 127) * 256 + (i >> 7)]);
    } else {  // Wt2[n][k] = bf16(W2[k][n]), K=256
        int lid = (b - WT2_B0) * 256 + tid;
        for (int i = lid; i < 256 * 256; i += WT2_NB * 256)
            Wt2[i] = f2bf(W2[(size_t)(i & 255) * 256 + (i >> 8)]);
    }
}

// ---------------- ELL build: 256-node groups, full tile staged in LDS ----------------

__launch_bounds__(256)
__global__ void build_kernel(const unsigned* __restrict__ partE,
                             const int* __restrict__ cursor,
                             int* __restrict__ cnt, unsigned short* __restrict__ eidx,
                             int N) {
    __shared__ unsigned short es[256 * MAXDEG];  // 32KB ELL tile
    __shared__ unsigned hist[256];
    int g = blockIdx.x, tid = threadIdx.x;
    hist[tid] = 0;
    __syncthreads();
    int ec = cursor[g]; if (ec > GCAP) ec = GCAP;
    const unsigned* pe = partE + (size_t)g * GCAP;
    for (int i = tid; i < ec; i += 256) {
        unsigned p = pe[i];
        int dl = (int)(p & 255);
        int s = (int)(p >> GSHIFT);
        unsigned r = atomicAdd(&hist[dl], 1u);
        if (r < MAXDEG)  // statistically unreachable (max deg ~40)
            es[dl * MAXDEG + r] = (unsigned short)s;
    }
    __syncthreads();
    // flush: 256 rows x 128B = 2048 x 16B (eidx padded to ngrp*256 rows)
    const u32x4* s4 = (const u32x4*)es;
    u32x4* d4 = (u32x4*)(eidx + ((size_t)g << GSHIFT) * MAXDEG);
    for (int i = tid; i < 2048; i += 256)
        __builtin_nontemporal_store(s4[i], &d4[i]);
    int node = (g << GSHIFT) + tid;
    if (node < N) cnt[node] = (int)hist[tid];
}

// ---------------- mean aggregation: one wave per dst node, ELL edge table ----------------
// CLOSED at the ~11 cyc/128B-line/CU service floor. n0/nLim allow node-range
// splitting (R27: agg256 split in two so top-5 reveals the #2 dispatch).

template <int D>
__global__ void agg_mean_bf16_kernel(const unsigned short* __restrict__ feat,
                                     const int* __restrict__ cnt,
                                     const unsigned short* __restrict__ eidx,
                                     unsigned short* __restrict__ out, int nLim, int n0) {
    constexpr int VPL = D / 64;  // 2 or 4
    int wave = n0 + blockIdx.x * (blockDim.x >> 6) + (threadIdx.x >> 6);
    int lane = threadIdx.x & 63;
    if (wave >= nLim) return;
    int deg = cnt[wave];
    int stored = deg > MAXDEG ? MAXDEG : deg;
    const unsigned short* row = eidx + (size_t)wave * MAXDEG;
    int myIdx = (lane < stored) ? (int)row[lane] : 0;

    float acc[VPL];
    #pragma unroll
    for (int i = 0; i < VPL; ++i) acc[i] = 0.0f;

    int j = 0;
    for (; j + 8 <= stored; j += 8) {
        if constexpr (VPL == 2) {
            unsigned v[8];
            #pragma unroll
            for (int u = 0; u < 8; ++u) {
                int s = __shfl(myIdx, j + u, 64);
                v[u] = *(const unsigned*)(feat + (size_t)s * D + lane * 2);
            }
            #pragma unroll
            for (int u = 0; u < 8; ++u) { acc[0] += bflo(v[u]); acc[1] += bfhi(v[u]); }
        } else {
            uint2 v[8];
            #pragma unroll
            for (int u = 0; u < 8; ++u) {
                int s = __shfl(myIdx, j + u, 64);
                v[u] = *(const uint2*)(feat + (size_t)s * D + lane * 4);
            }
            #pragma unroll
            for (int u = 0; u < 8; ++u) {
                acc[0] += bflo(v[u].x); acc[1] += bfhi(v[u].x);
                acc[2] += bflo(v[u].y); acc[3] += bfhi(v[u].y);
            }
        }
    }
    for (; j < stored; ++j) {
        int s = __shfl(myIdx, j, 64);
        if constexpr (VPL == 2) {
            unsigned v = *(const unsigned*)(feat + (size_t)s * D + lane * 2);
            acc[0] += bflo(v); acc[1] += bfhi(v);
        } else {
            uint2 v = *(const uint2*)(feat + (size_t)s * D + lane * 4);
            acc[0] += bflo(v.x); acc[1] += bfhi(v.x);
            acc[2] += bflo(v.y); acc[3] += bfhi(v.y);
        }
    }

    float invd = 1.0f / (float)(deg > 0 ? deg : 1);  // true-degree divisor
    if constexpr (VPL == 2) {
        unsigned o = (unsigned)f2bf(acc[0] * invd) | ((unsigned)f2bf(acc[1] * invd) << 16);
        __builtin_nontemporal_store(o, (unsigned*)(out + (size_t)wave * D + lane * 2));
    } else {
        unsigned lo = (unsigned)f2bf(acc[0] * invd) | ((unsigned)f2bf(acc[1] * invd) << 16);
        unsigned hi = (unsigned)f2bf(acc[2] * invd) | ((unsigned)f2bf(acc[3] * invd) << 16);
        unsigned long long o = (unsigned long long)lo | ((unsigned long long)hi << 32);
        __builtin_nontemporal_store(o, (unsigned long long*)(out + (size_t)wave * D + lane * 4));
    }
}

// ---------------- bf16 MFMA GEMM + bias + ReLU ----------------
// MODE 0: store bf16 to Cb.  MODE 1: fused per-graph-sum epilogue
// (shfl-reduced, one atomicAdd per (col,graph) per block).

template <int K, int MODE>
__launch_bounds__(256)
__global__ void gemm_mfma_kernel(const unsigned short* __restrict__ A,
                                 const unsigned short* __restrict__ Wt,
                                 const float* __restrict__ bias,
                                 unsigned short* __restrict__ Cb,
                                 const int* __restrict__ gids,
                                 float* __restrict__ gsum,
                                 int N) {
    constexpr int LDS = 40;
    __shared__ unsigned short As[64 * LDS];
    __shared__ unsigned short Bs[256 * LDS];

    int tid = threadIdx.x;
    int wave = tid >> 6;
    int lane = tid & 63;
    int m = lane & 15;
    int q = lane >> 4;
    int rowBase = blockIdx.x * 64;

    f32x4 acc[4][4] = {};

    for (int kc = 0; kc < K; kc += 32) {
        {
            int r = tid >> 2;
            int seg = tid & 3;
            int gr = rowBase + r;
            uint4 v = make_uint4(0, 0, 0, 0);
            if (gr < N) v = *(const uint4*)(A + (size_t)gr * K + kc + seg * 8);
            *(uint4*)&As[r * LDS + seg * 8] = v;
        }
        #pragma unroll
        for (int it = 0; it < 4; ++it) {
            int n = (tid >> 2) + it * 64;
            int seg = tid & 3;
            uint4 v = *(const uint4*)(Wt + (size_t)n * K + kc + seg * 8);
            *(uint4*)&Bs[n * LDS + seg * 8] = v;
        }
        __syncthreads();

        bf16x8 af[4], bfr[4];
        #pragma unroll
        for (int r = 0; r < 4; ++r)
            af[r] = *(const bf16x8*)&As[(r * 16 + m) * LDS + q * 8];
        #pragma unroll
        for (int c = 0; c < 4; ++c)
            bfr[c] = *(const bf16x8*)&Bs[(wave * 64 + c * 16 + m) * LDS + q * 8];
        #pragma unroll
        for (int r = 0; r < 4; ++r)
            #pragma unroll
            for (int c = 0; c < 4; ++c)
                acc[r][c] = __builtin_amdgcn_mfma_f32_16x16x32_bf16(af[r], bfr[c], acc[r][c], 0, 0, 0);
        __syncthreads();
    }

    if constexpr (MODE == 0) {
        #pragma unroll
        for (int c = 0; c < 4; ++c) {
            int col = wave * 64 + c * 16 + m;
            float bv = bias[col];
            #pragma unroll
            for (int r = 0; r < 4; ++r) {
                #pragma unroll
                for (int reg = 0; reg < 4; ++reg) {
                    int grow = rowBase + r * 16 + q * 4 + reg;
                    if (grow < N)
                        Cb[(size_t)grow * 256 + col] = f2bf(fmaxf(acc[r][c][reg] + bv, 0.0f));
                }
            }
        }
    } else {
        int* sgid = (int*)As;
        if (tid < 64) {
            int gr = rowBase + tid;
            sgid[tid] = (gr < N) ? gids[gr] : 0x7fffffff;
        }
        __syncthreads();
        int lastValid = N - 1 - rowBase;
        if (lastValid > 63) lastValid = 63;
        int gmin = sgid[0];
        int gmax = sgid[lastValid];
        #pragma unroll
        for (int c = 0; c < 4; ++c) {
            int col = wave * 64 + c * 16 + m;
            float bv = bias[col];
            for (int g = gmin; g <= gmax; ++g) {
                float p = 0.0f;
                #pragma unroll
                for (int r = 0; r < 4; ++r) {
                    #pragma unroll
                    for (int reg = 0; reg < 4; ++reg) {
                        int lr = r * 16 + q * 4 + reg;
                        if (sgid[lr] == g)
                            p += fmaxf(acc[r][c][reg] + bv, 0.0f);
                    }
                }
                p += __shfl_xor(p, 16, 64);
                p += __shfl_xor(p, 32, 64);
                if (q == 0 && p != 0.0f)
                    atomicAdd(&gsum[g * 256 + col], p);
            }
        }
    }
}

// ---------------- MLP head ----------------

__global__ void final_kernel(const float* __restrict__ gsum, const int* __restrict__ gstart,
                             const float* __restrict__ Wr1, const float* __restrict__ br1,
                             const float* __restrict__ Wr2, const float* __restrict__ br2,
                             float* __restrict__ out) {
    __shared__ float part[512];
    __shared__ float ws2[2];
    int g = blockIdx.x;
    int t = threadIdx.x;  // 512
    int j = t & 127;
    int kq = t >> 7;
    int c = gstart[g + 1] - gstart[g];
    float invc = 1.0f / (float)(c > 0 ? c : 1);
    const float* gs = gsum + g * 256;
    float acc = 0.0f;
    #pragma unroll 8
    for (int k = kq * 64; k < kq * 64 + 64; ++k)
        acc += gs[k] * Wr1[k * 128 + j];
    part[t] = acc;
    __syncthreads();
    if (t < 128) {
        float s = part[j] + part[128 + j] + part[256 + j] + part[384 + j];
        float p = (s * invc + br1[j]) * Wr2[j];
        #pragma unroll
        for (int d = 32; d > 0; d >>= 1) p += __shfl_down(p, d, 64);
        if ((t & 63) == 0) ws2[t >> 6] = p;
    }
    __syncthreads();
    if (t == 0) out[g] = ws2[0] + ws2[1] + br2[0];
}

// ---------------- launch ----------------

extern "C" void kernel_launch(void* const* d_in, const int* in_sizes, int n_in,
                              void* d_out, int out_size, void* d_ws, size_t ws_size,
                              hipStream_t stream) {
    const float* h    = (const float*)d_in[0];
    const int*   src  = (const int*)d_in[1];
    const int*   dst  = (const int*)d_in[2];
    const int*   gids = (const int*)d_in[3];
    const float* W1   = (const float*)d_in[4];
    const float* b1   = (const float*)d_in[5];
    const float* W2   = (const float*)d_in[6];
    const float* b2   = (const float*)d_in[7];
    const float* Wr1  = (const float*)d_in[8];
    const float* br1  = (const float*)d_in[9];
    const float* Wr2  = (const float*)d_in[10];
    const float* br2  = (const float*)d_in[11];

    int N = in_sizes[0] / 128;
    int E = in_sizes[1];
    int ngrp = (N + 255) >> GSHIFT;  // 196 for N=50000 (must be <= 256)

    // workspace ([gsum|cursor] contiguous for a single memset)
    char* w = (char*)d_ws;
    unsigned short* hb     = (unsigned short*)w;  w += (size_t)N * 128 * sizeof(unsigned short);
    unsigned short* h1b    = (unsigned short*)w;  w += (size_t)N * 256 * sizeof(unsigned short);
    unsigned short* aggOut = (unsigned short*)w;  w += (size_t)N * 256 * sizeof(unsigned short);
    int* cnt    = (int*)w;              w += (size_t)N * sizeof(int);
    float* gsum = (float*)w;            w += (size_t)NUM_GRAPHS * 256 * sizeof(float);
    int* cursor = (int*)w;              w += 256 * sizeof(int);
    unsigned short* eidx = (unsigned short*)w;  w += (size_t)ngrp * 256 * MAXDEG * sizeof(unsigned short);
    unsigned short* Wt1 = (unsigned short*)w;   w += 256 * 128 * sizeof(unsigned short);
    unsigned short* Wt2 = (unsigned short*)w;   w += 256 * 256 * sizeof(unsigned short);
    int* gstart = (int*)w;              w += (size_t)(NUM_GRAPHS + 1) * sizeof(int);
    // partE aliases aggOut: partE live = dispatches 2-3, aggOut live from 4 on.
    unsigned* partE = (unsigned*)aggOut;

    // 1) zero gsum+cursor in one shot
    (void)hipMemsetAsync(gsum, 0,
                         (size_t)NUM_GRAPHS * 256 * sizeof(float) + 256 * sizeof(int),
                         stream);
    // 2) prep: compacted edge partition, gstart, h cast, weight transposes
    misc_kernel<<<MISC_NB, 256, 0, stream>>>(dst, src, gids, h, W1, W2, cursor, partE,
                                             gstart, hb, Wt1, Wt2, N, E);
    // 3) ELL build: LDS-staged tile, fully-coalesced global writes
    build_kernel<<<ngrp, 256, 0, stream>>>(partE, cursor, cnt, eidx, N);

    // 4-5) layer 1
    agg_mean_bf16_kernel<128><<<(N + 3) / 4, 256, 0, stream>>>(hb, cnt, eidx, aggOut, N, 0);
    gemm_mfma_kernel<128, 0><<<(N + 63) / 64, 256, 0, stream>>>(aggOut, Wt1, b1, h1b, nullptr, nullptr, N);

    // 6-7) layer 2 agg SPLIT into two node-range halves (~28us each: drops the
    // argmax dispatch below the middle kernels so top-5 reveals the true #2)
    int H = ((N / 2) + 3) & ~3;  // first-half node count, multiple of 4
    agg_mean_bf16_kernel<256><<<H / 4, 256, 0, stream>>>(h1b, cnt, eidx, aggOut, H, 0);
    agg_mean_bf16_kernel<256><<<(N - H + 3) / 4, 256, 0, stream>>>(h1b, cnt, eidx, aggOut, N, H);
    gemm_mfma_kernel<256, 1><<<(N + 63) / 64, 256, 0, stream>>>(aggOut, Wt2, b2, nullptr, gids, gsum, N);

    // 8) head
    final_kernel<<<NUM_GRAPHS, 512, 0, stream>>>(gsum, gstart, Wr1, br1, Wr2, br2, (float*)d_out);
}

// Round 14
// 279.069 us; speedup vs baseline: 1.4178x; 1.0186x over previous
//
#include <hip/hip_runtime.h>

// GCN regressor: 2x (mean-aggregate + linear+ReLU) + per-graph mean + MLP head.
// N=50000 nodes, E=800000 edges, D_IN=128, H1=256, H2=128, G=256.
// R28 = exact revert to R24 (best measured: 279.6us). R27's diagnostic split
// found the #2 dispatch = harness 256MiB workspace poison fill (41.8us,
// 80% HBM peak, per-iteration, untouchable). No kernel of ours between
// 41.6us and the ~28us agg halves -> budget closes:
//   aggs 82 (HW line-service floor) + fill 42 (harness) + prep/build ~40
//   + GEMMs ~20 + final/memset ~6 =~ 190; remainder = boundary/playback
//   overhead (R13/R25/R26 all failed to reclaim it; R25 spin was 2.5x WORSE).
// AGG MODEL (quantitative, closed): ~11 cyc per 128B line per CU.
//   agg256 3.2M lines -> 54.6 pred / 54.3 meas; agg128 1.6M lines -> ~28.
//   5 structural probes (R16-R19) all null or negative. Do not touch.
// Closed: R6 chunk-gather 7x; R8/R9 grid.sync 2x; R11 agg-GEMM fusion; R13
//   lookback merge; R16-R19 gather probes; R17 launch_bounds spill; R20
//   per-edge global atomics (55-62us); R21/R22 scattered 4B writes
//   (~30us/800K invariant); R25 spin barrier (140us); R26 sync-free merge
//   (neutral-negative); R27 agg split (+4.7us, diagnostic only).

#define NUM_GRAPHS 256
#define MAXDEG 64
#define GSHIFT 8              // 256-node groups
#define GCAP 4864             // per-group edge capacity (mean 4082, +12 sigma)
#define CHUNK_MAX 3200        // per-block edge chunk cap (E=800000/256 = 3125)

// misc_kernel block partition
#define PART_B0 0
#define PART_NB 256
#define CST_B0 (PART_B0 + PART_NB)
#define CST_NB 512
#define GST_B0 (CST_B0 + CST_NB)
#define GST_NB 64
#define WT1_B0 (GST_B0 + GST_NB)
#define WT1_NB 16
#define WT2_B0 (WT1_B0 + WT1_NB)
#define WT2_NB 32
#define MISC_NB (WT2_B0 + WT2_NB)

typedef __attribute__((ext_vector_type(8))) short bf16x8;
typedef __attribute__((ext_vector_type(4))) float f32x4;
typedef __attribute__((ext_vector_type(4))) unsigned int u32x4;

__device__ inline unsigned short f2bf(float f) {  // round-to-nearest-even
    unsigned u = __float_as_uint(f);
    return (unsigned short)((u + 0x7fff + ((u >> 16) & 1)) >> 16);
}
__device__ inline float bflo(unsigned u) { return __uint_as_float(u << 16); }
__device__ inline float bfhi(unsigned u) { return __uint_as_float(u & 0xffff0000u); }

// ---------------- misc: edge partition (compacted) + gstart + h cast + weight transposes ----------------

__launch_bounds__(256)
__global__ void misc_kernel(const int* __restrict__ dst, const int* __restrict__ src,
                            const int* __restrict__ gids,
                            const float* __restrict__ h,
                            const float* __restrict__ W1, const float* __restrict__ W2,
                            int* __restrict__ cursor, unsigned* __restrict__ partE,
                            int* __restrict__ gstart,
                            unsigned short* __restrict__ hb,
                            unsigned short* __restrict__ Wt1, unsigned short* __restrict__ Wt2,
                            int N, int E) {
    int b = blockIdx.x, tid = threadIdx.x;
    if (b < CST_B0) {  // partition: hist -> scan -> LDS compaction -> coalesced flush
        __shared__ unsigned lcnt[256];
        __shared__ unsigned sbuf[256];
        __shared__ unsigned lbase[257];
        __shared__ unsigned gb[256];
        __shared__ unsigned comp[CHUNK_MAX];
        int b0 = b - PART_B0;
        int chunk = (E + PART_NB - 1) / PART_NB;
        int ebeg = b0 * chunk;
        int eend = ebeg + chunk; if (eend > E) eend = E;
        int ecount = eend - ebeg; if (ecount < 0) ecount = 0;

        lcnt[tid] = 0;
        __syncthreads();
        for (int e = ebeg + tid; e < eend; e += 256) {
            int d = __builtin_nontemporal_load(&dst[e]);
            atomicAdd(&lcnt[d >> GSHIFT], 1u);
        }
        __syncthreads();
        // Kogge-Stone inclusive scan over 256 bins -> exclusive lbase
        unsigned v = lcnt[tid];
        sbuf[tid] = v;
        __syncthreads();
        #pragma unroll
        for (int dd = 1; dd < 256; dd <<= 1) {
            unsigned t = (tid >= dd) ? sbuf[tid - dd] : 0u;
            __syncthreads();
            sbuf[tid] += t;
            __syncthreads();
        }
        lbase[tid] = sbuf[tid] - v;
        if (tid == 255) lbase[256] = sbuf[255];
        // claim global run per non-empty group; reset lcnt for sweep 2
        gb[tid] = v ? (unsigned)atomicAdd(&cursor[tid], (int)v) : 0u;
        lcnt[tid] = 0;
        __syncthreads();
        // sweep 2: LDS scatter into group-ordered compacted buffer
        for (int e = ebeg + tid; e < eend; e += 256) {
            int d = __builtin_nontemporal_load(&dst[e]);
            int s = __builtin_nontemporal_load(&src[e]);
            int g = d >> GSHIFT;
            unsigned r = atomicAdd(&lcnt[g], 1u) + lbase[g];
            if (r < (unsigned)CHUNK_MAX)  // always true for E=800000
                comp[r] = ((unsigned)s << GSHIFT) | (unsigned)(d & 255);
        }
        __syncthreads();
        // coalesced flush: consecutive i in a run -> consecutive global addrs
        for (int i = tid; i < ecount; i += 256) {
            int lo = 0, hi = 256;
            while (hi - lo > 1) {  // find g: lbase[g] <= i < lbase[g+1]
                int mid = (lo + hi) >> 1;
                if (lbase[mid] <= (unsigned)i) lo = mid; else hi = mid;
            }
            unsigned dest = (unsigned)lo * GCAP + gb[lo] + ((unsigned)i - lbase[lo]);
            if (dest < (unsigned)(256 * GCAP))
                __builtin_nontemporal_store(comp[i], &partE[dest]);
        }
    } else if (b < GST_B0) {  // cast h -> bf16 (float4 granules)
        int lid = (b - CST_B0) * 256 + tid;
        int total4 = N * 32;
        for (int i = lid; i < total4; i += CST_NB * 256) {
            float4 v = *(const float4*)(h + (size_t)i * 4);
            ushort4 o;
            o.x = f2bf(v.x); o.y = f2bf(v.y); o.z = f2bf(v.z); o.w = f2bf(v.w);
            *(ushort4*)(hb + (size_t)i * 4) = o;
        }
    } else if (b < WT1_B0) {  // graph segment starts (gids sorted)
        int lid = (b - GST_B0) * 256 + tid;
        for (int n = lid; n < N; n += GST_NB * 256) {
            int g = gids[n];
            int gp = (n == 0) ? -1 : gids[n - 1];
            for (int x = gp + 1; x <= g; ++x) gstart[x] = n;
            if (n == N - 1)
                for (int x = g + 1; x <= NUM_GRAPHS; ++x) gstart[x] = N;
        }
    } else if (b < WT2_B0) {  // Wt1[n][k] = bf16(W1[k][n]), K=128
        int lid = (b - WT1_B0) * 256 + tid;
        for (int i = lid; i < 256 * 128; i += WT1_NB * 256)
            Wt1[i] = f2bf(W1[(size_t)(i & 127) * 256 + (i >> 7)]);
    } else {  // Wt2[n][k] = bf16(W2[k][n]), K=256
        int lid = (b - WT2_B0) * 256 + tid;
        for (int i = lid; i < 256 * 256; i += WT2_NB * 256)
            Wt2[i] = f2bf(W2[(size_t)(i & 255) * 256 + (i >> 8)]);
    }
}

// ---------------- ELL build: 256-node groups, full tile staged in LDS ----------------
// Rank scatter is LDS-local (32KB tile); global flush is a straight u32x4
// stream (fully coalesced). No scattered global writes anywhere.

__launch_bounds__(256)
__global__ void build_kernel(const unsigned* __restrict__ partE,
                             const int* __restrict__ cursor,
                             int* __restrict__ cnt, unsigned short* __restrict__ eidx,
                             int N) {
    __shared__ unsigned short es[256 * MAXDEG];  // 32KB ELL tile
    __shared__ unsigned hist[256];
    int g = blockIdx.x, tid = threadIdx.x;
    hist[tid] = 0;
    __syncthreads();
    int ec = cursor[g]; if (ec > GCAP) ec = GCAP;
    const unsigned* pe = partE + (size_t)g * GCAP;
    for (int i = tid; i < ec; i += 256) {
        unsigned p = pe[i];
        int dl = (int)(p & 255);
        int s = (int)(p >> GSHIFT);
        unsigned r = atomicAdd(&hist[dl], 1u);
        if (r < MAXDEG)  // statistically unreachable (max deg ~40)
            es[dl * MAXDEG + r] = (unsigned short)s;
    }
    __syncthreads();
    // flush: 256 rows x 128B = 2048 x 16B (eidx padded to ngrp*256 rows)
    const u32x4* s4 = (const u32x4*)es;
    u32x4* d4 = (u32x4*)(eidx + ((size_t)g << GSHIFT) * MAXDEG);
    for (int i = tid; i < 2048; i += 256)
        __builtin_nontemporal_store(s4[i], &d4[i]);
    int node = (g << GSHIFT) + tid;
    if (node < N) cnt[node] = (int)hist[tid];
}

// ---------------- mean aggregation: one wave per dst node, ELL edge table ----------------
// CLOSED at the ~11 cyc/128B-line/CU service floor (54.3us = 3.2M lines).

template <int D>
__global__ void agg_mean_bf16_kernel(const unsigned short* __restrict__ feat,
                                     const int* __restrict__ cnt,
                                     const unsigned short* __restrict__ eidx,
                                     unsigned short* __restrict__ out, int N) {
    constexpr int VPL = D / 64;  // 2 or 4
    int wave = blockIdx.x * (blockDim.x >> 6) + (threadIdx.x >> 6);
    int lane = threadIdx.x & 63;
    if (wave >= N) return;
    int deg = cnt[wave];
    int stored = deg > MAXDEG ? MAXDEG : deg;
    const unsigned short* row = eidx + (size_t)wave * MAXDEG;
    int myIdx = (lane < stored) ? (int)row[lane] : 0;

    float acc[VPL];
    #pragma unroll
    for (int i = 0; i < VPL; ++i) acc[i] = 0.0f;

    int j = 0;
    for (; j + 8 <= stored; j += 8) {
        if constexpr (VPL == 2) {
            unsigned v[8];
            #pragma unroll
            for (int u = 0; u < 8; ++u) {
                int s = __shfl(myIdx, j + u, 64);
                v[u] = *(const unsigned*)(feat + (size_t)s * D + lane * 2);
            }
            #pragma unroll
            for (int u = 0; u < 8; ++u) { acc[0] += bflo(v[u]); acc[1] += bfhi(v[u]); }
        } else {
            uint2 v[8];
            #pragma unroll
            for (int u = 0; u < 8; ++u) {
                int s = __shfl(myIdx, j + u, 64);
                v[u] = *(const uint2*)(feat + (size_t)s * D + lane * 4);
            }
            #pragma unroll
            for (int u = 0; u < 8; ++u) {
                acc[0] += bflo(v[u].x); acc[1] += bfhi(v[u].x);
                acc[2] += bflo(v[u].y); acc[3] += bfhi(v[u].y);
            }
        }
    }
    for (; j < stored; ++j) {
        int s = __shfl(myIdx, j, 64);
        if constexpr (VPL == 2) {
            unsigned v = *(const unsigned*)(feat + (size_t)s * D + lane * 2);
            acc[0] += bflo(v); acc[1] += bfhi(v);
        } else {
            uint2 v = *(const uint2*)(feat + (size_t)s * D + lane * 4);
            acc[0] += bflo(v.x); acc[1] += bfhi(v.x);
            acc[2] += bflo(v.y); acc[3] += bfhi(v.y);
        }
    }

    float invd = 1.0f / (float)(deg > 0 ? deg : 1);  // true-degree divisor
    if constexpr (VPL == 2) {
        unsigned o = (unsigned)f2bf(acc[0] * invd) | ((unsigned)f2bf(acc[1] * invd) << 16);
        __builtin_nontemporal_store(o, (unsigned*)(out + (size_t)wave * D + lane * 2));
    } else {
        unsigned lo = (unsigned)f2bf(acc[0] * invd) | ((unsigned)f2bf(acc[1] * invd) << 16);
        unsigned hi = (unsigned)f2bf(acc[2] * invd) | ((unsigned)f2bf(acc[3] * invd) << 16);
        unsigned long long o = (unsigned long long)lo | ((unsigned long long)hi << 32);
        __builtin_nontemporal_store(o, (unsigned long long*)(out + (size_t)wave * D + lane * 4));
    }
}

// ---------------- bf16 MFMA GEMM + bias + ReLU ----------------
// MODE 0: store bf16 to Cb.  MODE 1: fused per-graph-sum epilogue
// (shfl-reduced, one atomicAdd per (col,graph) per block).

template <int K, int MODE>
__launch_bounds__(256)
__global__ void gemm_mfma_kernel(const unsigned short* __restrict__ A,
                                 const unsigned short* __restrict__ Wt,
                                 const float* __restrict__ bias,
                                 unsigned short* __restrict__ Cb,
                                 const int* __restrict__ gids,
                                 float* __restrict__ gsum,
                                 int N) {
    constexpr int LDS = 40;
    __shared__ unsigned short As[64 * LDS];
    __shared__ unsigned short Bs[256 * LDS];

    int tid = threadIdx.x;
    int wave = tid >> 6;
    int lane = tid & 63;
    int m = lane & 15;
    int q = lane >> 4;
    int rowBase = blockIdx.x * 64;

    f32x4 acc[4][4] = {};

    for (int kc = 0; kc < K; kc += 32) {
        {
            int r = tid >> 2;
            int seg = tid & 3;
            int gr = rowBase + r;
            uint4 v = make_uint4(0, 0, 0, 0);
            if (gr < N) v = *(const uint4*)(A + (size_t)gr * K + kc + seg * 8);
            *(uint4*)&As[r * LDS + seg * 8] = v;
        }
        #pragma unroll
        for (int it = 0; it < 4; ++it) {
            int n = (tid >> 2) + it * 64;
            int seg = tid & 3;
            uint4 v = *(const uint4*)(Wt + (size_t)n * K + kc + seg * 8);
            *(uint4*)&Bs[n * LDS + seg * 8] = v;
        }
        __syncthreads();

        bf16x8 af[4], bfr[4];
        #pragma unroll
        for (int r = 0; r < 4; ++r)
            af[r] = *(const bf16x8*)&As[(r * 16 + m) * LDS + q * 8];
        #pragma unroll
        for (int c = 0; c < 4; ++c)
            bfr[c] = *(const bf16x8*)&Bs[(wave * 64 + c * 16 + m) * LDS + q * 8];
        #pragma unroll
        for (int r = 0; r < 4; ++r)
            #pragma unroll
            for (int c = 0; c < 4; ++c)
                acc[r][c] = __builtin_amdgcn_mfma_f32_16x16x32_bf16(af[r], bfr[c], acc[r][c], 0, 0, 0);
        __syncthreads();
    }

    if constexpr (MODE == 0) {
        #pragma unroll
        for (int c = 0; c < 4; ++c) {
            int col = wave * 64 + c * 16 + m;
            float bv = bias[col];
            #pragma unroll
            for (int r = 0; r < 4; ++r) {
                #pragma unroll
                for (int reg = 0; reg < 4; ++reg) {
                    int grow = rowBase + r * 16 + q * 4 + reg;
                    if (grow < N)
                        Cb[(size_t)grow * 256 + col] = f2bf(fmaxf(acc[r][c][reg] + bv, 0.0f));
                }
            }
        }
    } else {
        int* sgid = (int*)As;
        if (tid < 64) {
            int gr = rowBase + tid;
            sgid[tid] = (gr < N) ? gids[gr] : 0x7fffffff;
        }
        __syncthreads();
        int lastValid = N - 1 - rowBase;
        if (lastValid > 63) lastValid = 63;
        int gmin = sgid[0];
        int gmax = sgid[lastValid];
        #pragma unroll
        for (int c = 0; c < 4; ++c) {
            int col = wave * 64 + c * 16 + m;
            float bv = bias[col];
            for (int g = gmin; g <= gmax; ++g) {
                float p = 0.0f;
                #pragma unroll
                for (int r = 0; r < 4; ++r) {
                    #pragma unroll
                    for (int reg = 0; reg < 4; ++reg) {
                        int lr = r * 16 + q * 4 + reg;
                        if (sgid[lr] == g)
                            p += fmaxf(acc[r][c][reg] + bv, 0.0f);
                    }
                }
                p += __shfl_xor(p, 16, 64);
                p += __shfl_xor(p, 32, 64);
                if (q == 0 && p != 0.0f)
                    atomicAdd(&gsum[g * 256 + col], p);
            }
        }
    }
}

// ---------------- MLP head ----------------
// 512 threads: 4-way k-split (j = t&127, kq = t>>7 handles 64 ks) + LDS
// combine. 8 waves/CU: the 64-deep Wr1 load chain gets hidden.

__global__ void final_kernel(const float* __restrict__ gsum, const int* __restrict__ gstart,
                             const float* __restrict__ Wr1, const float* __restrict__ br1,
                             const float* __restrict__ Wr2, const float* __restrict__ br2,
                             float* __restrict__ out) {
    __shared__ float part[512];
    __shared__ float ws2[2];
    int g = blockIdx.x;
    int t = threadIdx.x;  // 512
    int j = t & 127;
    int kq = t >> 7;
    int c = gstart[g + 1] - gstart[g];
    float invc = 1.0f / (float)(c > 0 ? c : 1);
    const float* gs = gsum + g * 256;
    float acc = 0.0f;
    #pragma unroll 8
    for (int k = kq * 64; k < kq * 64 + 64; ++k)
        acc += gs[k] * Wr1[k * 128 + j];
    part[t] = acc;
    __syncthreads();
    if (t < 128) {
        float s = part[j] + part[128 + j] + part[256 + j] + part[384 + j];
        float p = (s * invc + br1[j]) * Wr2[j];
        #pragma unroll
        for (int d = 32; d > 0; d >>= 1) p += __shfl_down(p, d, 64);
        if ((t & 63) == 0) ws2[t >> 6] = p;
    }
    __syncthreads();
    if (t == 0) out[g] = ws2[0] + ws2[1] + br2[0];
}

// ---------------- launch ----------------

extern "C" void kernel_launch(void* const* d_in, const int* in_sizes, int n_in,
                              void* d_out, int out_size, void* d_ws, size_t ws_size,
                              hipStream_t stream) {
    const float* h    = (const float*)d_in[0];
    const int*   src  = (const int*)d_in[1];
    const int*   dst  = (const int*)d_in[2];
    const int*   gids = (const int*)d_in[3];
    const float* W1   = (const float*)d_in[4];
    const float* b1   = (const float*)d_in[5];
    const float* W2   = (const float*)d_in[6];
    const float* b2   = (const float*)d_in[7];
    const float* Wr1  = (const float*)d_in[8];
    const float* br1  = (const float*)d_in[9];
    const float* Wr2  = (const float*)d_in[10];
    const float* br2  = (const float*)d_in[11];

    int N = in_sizes[0] / 128;
    int E = in_sizes[1];
    int ngrp = (N + 255) >> GSHIFT;  // 196 for N=50000 (must be <= 256)

    // workspace ([gsum|cursor] contiguous for a single memset)
    char* w = (char*)d_ws;
    unsigned short* hb     = (unsigned short*)w;  w += (size_t)N * 128 * sizeof(unsigned short);
    unsigned short* h1b    = (unsigned short*)w;  w += (size_t)N * 256 * sizeof(unsigned short);
    unsigned short* aggOut = (unsigned short*)w;  w += (size_t)N * 256 * sizeof(unsigned short);
    int* cnt    = (int*)w;              w += (size_t)N * sizeof(int);
    float* gsum = (float*)w;            w += (size_t)NUM_GRAPHS * 256 * sizeof(float);
    int* cursor = (int*)w;              w += 256 * sizeof(int);
    unsigned short* eidx = (unsigned short*)w;  w += (size_t)ngrp * 256 * MAXDEG * sizeof(unsigned short);
    unsigned short* Wt1 = (unsigned short*)w;   w += 256 * 128 * sizeof(unsigned short);
    unsigned short* Wt2 = (unsigned short*)w;   w += 256 * 256 * sizeof(unsigned short);
    int* gstart = (int*)w;              w += (size_t)(NUM_GRAPHS + 1) * sizeof(int);
    // partE aliases aggOut: partE live = dispatches 2-3, aggOut live from 4 on.
    // (256*GCAP*4B = 4.98MB < 25.6MB)
    unsigned* partE = (unsigned*)aggOut;

    // 1) zero gsum+cursor in one shot (cnt fully written by build_kernel)
    (void)hipMemsetAsync(gsum, 0,
                         (size_t)NUM_GRAPHS * 256 * sizeof(float) + 256 * sizeof(int),
                         stream);
    // 2) prep: compacted edge partition, gstart, h cast, weight transposes
    misc_kernel<<<MISC_NB, 256, 0, stream>>>(dst, src, gids, h, W1, W2, cursor, partE,
                                             gstart, hb, Wt1, Wt2, N, E);
    // 3) ELL build: LDS-staged tile, fully-coalesced global writes
    build_kernel<<<ngrp, 256, 0, stream>>>(partE, cursor, cnt, eidx, N);

    // 4-5) layer 1
    agg_mean_bf16_kernel<128><<<(N + 3) / 4, 256, 0, stream>>>(hb, cnt, eidx, aggOut, N);
    gemm_mfma_kernel<128, 0><<<(N + 63) / 64, 256, 0, stream>>>(aggOut, Wt1, b1, h1b, nullptr, nullptr, N);

    // 6-7) layer 2 (readout fused into GEMM epilogue)
    agg_mean_bf16_kernel<256><<<(N + 3) / 4, 256, 0, stream>>>(h1b, cnt, eidx, aggOut, N);
    gemm_mfma_kernel<256, 1><<<(N + 63) / 64, 256, 0, stream>>>(aggOut, Wt2, b2, nullptr, gids, gsum, N);

    // 8) head
    final_kernel<<<NUM_GRAPHS, 512, 0, stream>>>(gsum, gstart, Wr1, br1, Wr2, br2, (float*)d_out);
}